// Round 6
// baseline (721.113 us; speedup 1.0000x reference)
//
#include <hip/hip_runtime.h>
#include <math.h>

// Keep box arithmetic bit-identical to numpy fp32 (no fma contraction):
// matching decisions (iou > 0.5, argmax) must not flip.
#pragma clang fp contract(off)

#define BB 64
#define AA 8732
#define GG 32

#define KC_GRID    768              // C role blocks
#define KC_CHUNKS  8732             // 64-row chunks, exact (64*8732/64)
#define CHUNK_F4   1296             // 64*81/4 float4 per chunk
#define KC_TRIPS   12               // ceil(8732/768)
#define KA1_PER    9                // ceil(8732/1024) blocks per image
#define KA1_BLOCKS (BB*KA1_PER)     // 576
#define KA2_BLOCKS (BB*2)           // 128 (16 pairs per 1024-thr block)
#define ROLE_A1    KC_GRID                         // 768
#define ROLE_A2    (KC_GRID+KA1_BLOCKS)            // 1344
#define ROLE_BE    (KC_GRID+KA1_BLOCKS+KA2_BLOCKS) // 1472
#define TOT_BLOCKS (ROLE_BE+BB)                    // 1536

// ---- workspace layout (bytes) ----
// [0,8192)           bestp  u32[B*G]
// [8192,567040)      bestg  u8[B*A]
// [567040,2802432)   cls_l  f32[B*A]
// [2802432,2806528)  ready  u32[64*16] (stride-16 to avoid line contention)
// [2806528,2806532)  ticket u32
// [2806536,2806544)  btot   f64
// [2806544,2806548)  np_acc i32
// control region [2802432,2806548) zeroed by kInit (stream-ordered first)

// Consumer-phase shared memory (union'd with producer-role overlays)
struct BESmem {
    unsigned int cl[AA];            // 34928 B radix keys
    unsigned int hist[256];
    float gcx[GG], gcy[GG], gw[GG], gh[GG];
    int glab[GG];
    unsigned int bp[GG];
    double red_d[16], red_p[16];
    double sh_loc, sh_pc;
    int red_i[16];
    unsigned int red_u[16];
    unsigned int sh_prefix, sh_remaining;
    int sh_np;
    unsigned char slab[AA];         // labels
};                                  // ~45.9 KB < 64 KB

__device__ __forceinline__ void iou_upd(const float4 an, int a,
    float gx1, float gy1, float gx2, float gy2, float gar2,
    float& bi, float& bu, int& ba)
{
    float ax1 = an.x - an.z / 2.0f, ay1 = an.y - an.w / 2.0f;
    float ax2 = an.x + an.z / 2.0f, ay2 = an.y + an.w / 2.0f;
    float aar = (ax2 - ax1) * (ay2 - ay1);
    float ltx = fmaxf(gx1, ax1), lty = fmaxf(gy1, ay1);
    float rbx = fminf(gx2, ax2), rby = fminf(gy2, ay2);
    float w = fmaxf(rbx - ltx, 0.0f), h = fmaxf(rby - lty, 0.0f);
    float inter = w * h;
    float uni = gar2 + aar - inter;
    if (inter * bu > bi * uni) { bi = inter; bu = uni; ba = a; }  // strict >: first max
}

// ---------------- kInit: zero control region (1029 u32) ----------------
__global__ __launch_bounds__(256) void kInit(unsigned int* __restrict__ z)
{
    for (int i = threadIdx.x; i < 1029; i += 256) z[i] = 0u;
}

// ---------------- kFused: producers + spin-wait consumers, one dispatch ----------------
// blocks [0,768):      C  — conf logsumexp, 64-row chunks, 1-deep reg prefetch.
//                      Per finished chunk: syncthreads (stores drained) ->
//                      threadfence (L2 writeback) -> atomicAdd ready[img].
//                      pend is RESET after each signal (round-5 bug: 11-chunk
//                      blocks double-signaled their last chunk -> consumers
//                      released early -> NaN from poisoned cls_l).
// blocks [768,1344):   A1 — per-anchor best gt (thread per anchor); flag/img.
// blocks [1344,1472):  A2 — per-gt best anchor (wave per (b,g)), 8x loads.
// blocks [1472,1536):  BE — consumer for image b: spins on ready[b] (atomic
//                      RMW + s_sleep) until 137/138 C + 9 A1 + 2 A2 signals,
//                      then threadfence (invalidate) and runs finalize +
//                      radix top-k + final reduce. Consumers are dispatched
//                      last; 64 blocks << 256 CUs -> no deadlock possible.
__global__ __launch_bounds__(1024, 4) void kFused(
    const float* __restrict__ loc_pred, const float* __restrict__ conf,
    const float* __restrict__ anchors, const float* __restrict__ gt_boxes,
    const int* __restrict__ gt_labels,
    unsigned char* __restrict__ bestg, unsigned int* __restrict__ bestp,
    float* __restrict__ cls_l, unsigned int* __restrict__ ready,
    unsigned int* __restrict__ ticket, double* __restrict__ btot_acc,
    int* __restrict__ np_acc, float* __restrict__ out)
{
    __shared__ __align__(16) unsigned char smem[sizeof(BESmem)];
    int tid = threadIdx.x;

    if (blockIdx.x < KC_GRID) {
        // ---- role C ----
        float* buf = (float*)smem;                // 20736 B overlay
        float4* buf4 = (float4*)smem;
        const float4* __restrict__ src4 = (const float4*)conf;
        float4 r0, r1;
        {   // prologue: stage chunk blockIdx.x
            size_t b4 = (size_t)blockIdx.x * CHUNK_F4;
            r0 = src4[b4 + tid];
            if (tid < CHUNK_F4 - 1024) r1 = src4[b4 + 1024 + tid];
            buf4[tid] = r0;
            if (tid < CHUNK_F4 - 1024) buf4[1024 + tid] = r1;
        }
        int pend = -1;
        for (int t = 0; t < KC_TRIPS; ++t) {      // uniform trips; barriers uncond.
            int c = blockIdx.x + t * KC_GRID;
            int nx = c + KC_GRID;
            bool hc = c < KC_CHUNKS, hn = nx < KC_CHUNKS;   // block-uniform
            __syncthreads();                      // staged LDS + prev stores drained
            if (pend >= 0) {                      // signal chunk computed last trip
                if (tid == 0) {
                    __threadfence();              // release: flush local L2
                    int i1 = (pend * 64) / AA, i2 = (pend * 64 + 63) / AA;
                    atomicAdd(&ready[i1 * 16], 1u);
                    if (i2 != i1) atomicAdd(&ready[i2 * 16], 1u);
                }
                pend = -1;                        // <- fix: signal exactly once
            }
            if (hn) {                             // issue next-chunk loads NOW
                size_t b4 = (size_t)nx * CHUNK_F4;
                r0 = src4[b4 + tid];
                if (tid < CHUNK_F4 - 1024) r1 = src4[b4 + 1024 + tid];
            }
            if (hc) {                             // compute chunk c: 16 lanes/row
                int r = tid >> 4, q = tid & 15;
                const float* row = buf + r * 81;  // 81 = 6 + 15*5 split
                float s;
                if (q == 0) {
                    s = __expf(row[0]) + __expf(row[1]) + __expf(row[2])
                      + __expf(row[3]) + __expf(row[4]) + __expf(row[5]);
                } else {
                    int ks = 6 + (q - 1) * 5;
                    s = __expf(row[ks]) + __expf(row[ks + 1]) + __expf(row[ks + 2])
                      + __expf(row[ks + 3]) + __expf(row[ks + 4]);
                }
                s += __shfl_xor(s, 1); s += __shfl_xor(s, 2);
                s += __shfl_xor(s, 4); s += __shfl_xor(s, 8);
                if (q == 0)
                    cls_l[c * 64 + r] = __logf(s) - row[0];  // idx01=0 for negatives
            }
            if (hn) {
                __syncthreads();                  // all lanes done reading buf
                buf4[tid] = r0;
                if (tid < CHUNK_F4 - 1024) buf4[1024 + tid] = r1;
            }
            if (hc) pend = c;                     // re-arm signal for next trip
        }
        __syncthreads();                          // final chunk's stores drained
        if (pend >= 0 && tid == 0) {              // only 12-chunk blocks reach here
            __threadfence();
            int i1 = (pend * 64) / AA, i2 = (pend * 64 + 63) / AA;
            atomicAdd(&ready[i1 * 16], 1u);
            if (i2 != i1) atomicAdd(&ready[i2 * 16], 1u);
        }
    } else if (blockIdx.x < ROLE_A2) {
        // ---- role A1 ---- (gt tiles overlay smem)
        float4* gco = (float4*)smem;              // 32 float4
        float* gar = (float*)smem + 128;          // 32 floats
        int blk = blockIdx.x - ROLE_A1;
        int b = blk / KA1_PER, ca = blk % KA1_PER;
        int a = ca * 1024 + tid;
        if (tid < GG) {
            float4 gb = ((const float4*)gt_boxes)[b * GG + tid];
            float x1 = gb.x - gb.z / 2.0f, y1 = gb.y - gb.w / 2.0f;
            float x2 = gb.x + gb.z / 2.0f, y2 = gb.y + gb.w / 2.0f;
            gco[tid] = make_float4(x1, y1, x2, y2);
            gar[tid] = (x2 - x1) * (y2 - y1);     // same rounding as reference
        }
        __syncthreads();
        if (a < AA) {                             // no early return (barrier below)
            float4 an = ((const float4*)anchors)[a];
            float ax1 = an.x - an.z / 2.0f, ay1 = an.y - an.w / 2.0f;
            float ax2 = an.x + an.z / 2.0f, ay2 = an.y + an.w / 2.0f;
            float aar = (ax2 - ax1) * (ay2 - ay1);
            float bi = -1.0f, bu = 1.0f; int bgi = 0;  // first compare takes g=0
#pragma unroll
            for (int g = 0; g < GG; ++g) {
                float4 cbox = gco[g];
                float ltx = fmaxf(cbox.x, ax1), lty = fmaxf(cbox.y, ay1);
                float rbx = fminf(cbox.z, ax2), rby = fminf(cbox.w, ay2);
                float w = fmaxf(rbx - ltx, 0.0f), h = fmaxf(rby - lty, 0.0f);
                float inter = w * h;
                float uni = gar[g] + aar - inter;
                if (inter * bu > bi * uni) { bi = inter; bu = uni; bgi = g; }
            }
            bestg[b * AA + a] = (2.0f * bi > bu) ? (unsigned char)bgi
                                                 : (unsigned char)0xFF;
        }
        __syncthreads();                          // all bestg stores drained
        if (tid == 0) { __threadfence(); atomicAdd(&ready[b * 16], 1u); }
    } else if (blockIdx.x < ROLE_BE) {
        // ---- role A2 ---- 16 waves/block, 16 pairs (half an image)
        int wv = tid >> 6, lane = tid & 63;
        int blk = blockIdx.x - ROLE_A2;
        int pair = blk * 16 + wv;                 // 0..2047, all same image b
        int b = pair >> 5, g = pair & 31;
        float4 gb = ((const float4*)gt_boxes)[b * GG + g];
        float gx1 = gb.x - gb.z / 2.0f, gy1 = gb.y - gb.w / 2.0f;
        float gx2 = gb.x + gb.z / 2.0f, gy2 = gb.y + gb.w / 2.0f;
        float gar2 = (gx2 - gx1) * (gy2 - gy1);
        const float4* __restrict__ A4 = (const float4*)anchors;
        float bi = -1.0f, bu = 1.0f; int ba = 0;
        // 8732 = 64*136 + 28; 136 = 8*17: a = lane + 64k ascending (tie order kept)
        for (int k0 = 0; k0 < 136; k0 += 8) {
            int a0 = lane + 64 * k0;
            float4 v0 = A4[a0];                   // 8 independent loads in flight
            float4 v1 = A4[a0 + 64];
            float4 v2 = A4[a0 + 128];
            float4 v3 = A4[a0 + 192];
            float4 v4 = A4[a0 + 256];
            float4 v5 = A4[a0 + 320];
            float4 v6 = A4[a0 + 384];
            float4 v7 = A4[a0 + 448];
            iou_upd(v0, a0,       gx1, gy1, gx2, gy2, gar2, bi, bu, ba);
            iou_upd(v1, a0 + 64,  gx1, gy1, gx2, gy2, gar2, bi, bu, ba);
            iou_upd(v2, a0 + 128, gx1, gy1, gx2, gy2, gar2, bi, bu, ba);
            iou_upd(v3, a0 + 192, gx1, gy1, gx2, gy2, gar2, bi, bu, ba);
            iou_upd(v4, a0 + 256, gx1, gy1, gx2, gy2, gar2, bi, bu, ba);
            iou_upd(v5, a0 + 320, gx1, gy1, gx2, gy2, gar2, bi, bu, ba);
            iou_upd(v6, a0 + 384, gx1, gy1, gx2, gy2, gar2, bi, bu, ba);
            iou_upd(v7, a0 + 448, gx1, gy1, gx2, gy2, gar2, bi, bu, ba);
        }
        if (lane < 28) {                          // tail: a = 8704..8731
            int a = 8704 + lane;
            iou_upd(A4[a], a, gx1, gy1, gx2, gy2, gar2, bi, bu, ba);
        }
        // wave butterfly-reduce, lexicographic (iou desc, a asc)
#pragma unroll
        for (int off = 32; off > 0; off >>= 1) {
            float oi = __shfl_down(bi, off);
            float ou = __shfl_down(bu, off);
            int   oa = __shfl_down(ba, off);
            float p1 = oi * bu, p2 = bi * ou;
            bool take = (p1 > p2) || ((p1 == p2) && (oa < ba));
            if (take) { bi = oi; bu = ou; ba = oa; }
        }
        if (lane == 0) bestp[pair] = (unsigned int)ba;
        __syncthreads();                          // all bestp stores drained
        if (tid == 0) { __threadfence(); atomicAdd(&ready[b * 16], 1u); }
    } else {
        // ---- role BE: consumer ----
        BESmem& S = *reinterpret_cast<BESmem*>(smem);
        int b = blockIdx.x - ROLE_BE, lane = tid & 63;
        if (tid == 0) {                           // spin until image b fully produced
            unsigned int tgt = (unsigned int)(((AA * (b + 1) - 1) >> 6)
                               - ((AA * b) >> 6) + 1 + KA1_PER + 2);
            while (atomicAdd(&ready[b * 16], 0u) < tgt)
                __builtin_amdgcn_s_sleep(2);
            __threadfence();                      // acquire: invalidate stale lines
        }
        __syncthreads();
        if (tid < GG) {
            float4 gb = ((const float4*)gt_boxes)[b * GG + tid];
            S.gcx[tid] = gb.x; S.gcy[tid] = gb.y; S.gw[tid] = gb.z; S.gh[tid] = gb.w;
            S.glab[tid] = gt_labels[b * GG + tid];
            S.bp[tid] = bestp[b * GG + tid];
        }
        __syncthreads();

        // ---- phase B: labels, loc loss, keys, positive CE ----
        double lsum = 0.0, pc = 0.0; int pcount = 0;
        for (int a = tid; a < AA; a += 1024) {
            int gf = -1;
#pragma unroll
            for (int g = 0; g < GG; ++g)
                if (S.bp[g] == (unsigned int)a) gf = g;  // ascending: largest g wins
            int gsel;
            if (gf >= 0) gsel = gf;
            else {
                unsigned char bg = bestg[b * AA + a];
                gsel = (bg == 0xFF) ? -1 : (int)bg;
            }
            int lab = 0;
            if (gsel >= 0) {
                lab = S.glab[gsel];               // labels in 1..C-1 -> positive
                float4 an = ((const float4*)anchors)[a];
                float e0 = (S.gcx[gsel] - an.x) / an.z;
                float e1 = (S.gcy[gsel] - an.y) / an.w;
                float e2 = logf(S.gw[gsel]) - logf(an.z);
                float e3 = logf(S.gh[gsel]) - logf(an.w);
                float4 lp = ((const float4*)loc_pred)[b * AA + a];
                float d0 = lp.x - e0, d1 = lp.y - e1, d2 = lp.z - e2, d3 = lp.w - e3;
                float t = 0.0f, ad;
                ad = fabsf(d0); t += (ad < 1.0f) ? 0.5f * d0 * d0 : ad - 0.5f;
                ad = fabsf(d1); t += (ad < 1.0f) ? 0.5f * d1 * d1 : ad - 0.5f;
                ad = fabsf(d2); t += (ad < 1.0f) ? 0.5f * d2 * d2 : ad - 0.5f;
                ad = fabsf(d3); t += (ad < 1.0f) ? 0.5f * d3 * d3 : ad - 0.5f;
                lsum += (double)t;
                pcount++;
            }
            S.slab[a] = (unsigned char)lab;
            float sv = cls_l[b * AA + a];
            if (lab > 0) {
                size_t rowb = ((size_t)(b * AA + a)) * 81;
                pc += (double)(sv + conf[rowb] - conf[rowb + lab]);  // lse - conf[lab]
                S.cl[a] = 0u;                     // positives excluded from mining
            } else {
                S.cl[a] = __float_as_uint(fmaxf(sv, 0.0f));  // guard tiny neg rounding
            }
        }
#pragma unroll
        for (int off = 32; off > 0; off >>= 1) {
            lsum += __shfl_down(lsum, off);
            pc += __shfl_down(pc, off);
            pcount += __shfl_down(pcount, off);
        }
        if (lane == 0) {
            S.red_d[tid >> 6] = lsum; S.red_p[tid >> 6] = pc; S.red_i[tid >> 6] = pcount;
        }
        __syncthreads();
        if (tid == 0) {
            double L = 0.0, C = 0.0; int P = 0;
            for (int w = 0; w < 16; ++w) { L += S.red_d[w]; C += S.red_p[w]; P += S.red_i[w]; }
            S.sh_loc = L; S.sh_pc = C; S.sh_np = P;
            S.sh_prefix = 0u;
            S.sh_remaining = (unsigned int)min(3 * P, AA - 1);
        }
        __syncthreads();
        int np_ = S.sh_np;
        int k = min(3 * np_, AA - 1);             // num_neg = min(3*num_pos, A-1)

        // ---- phase E: radix-select top-k (leader-ballot histogram) ----
        double topk = 0.0;
        int p_t_pos = 0;                          // positives inside neg_mask (tie at 0)
        if (k > 0) {
            for (int shift = 24; shift >= 0; shift -= 8) {
                if (tid < 256) S.hist[tid] = 0u;
                __syncthreads();
                unsigned int mask = (shift == 24) ? 0u : (0xFFFFFFFFu << (shift + 8));
                unsigned int pre = S.sh_prefix;
#pragma unroll
                for (int it = 0; it < 9; ++it) {  // 9*1024 >= 8732; wave-uniform trips
                    int i = tid + it * 1024;
                    bool in = (i < AA);
                    unsigned int u = in ? S.cl[i] : 0u;
                    bool act = in && ((u & mask) == pre);
                    unsigned int d = (u >> shift) & 255u;
                    unsigned long long actm = __ballot(act);
                    while (actm) {                // aggregate dominant digits
                        int src = __builtin_ctzll(actm);
                        unsigned int d0 = (unsigned int)__shfl((int)d, src);
                        unsigned long long m = __ballot(act && (d == d0));
                        int c = __popcll(m);
                        if (c < 8) break;         // spread digits -> per-lane fallback
                        if (lane == src) atomicAdd(&S.hist[d0], (unsigned int)c);
                        actm &= ~m;
                    }
                    if ((actm >> lane) & 1ull) atomicAdd(&S.hist[d], 1u);
                }
                __syncthreads();
                if (tid < 64) {                   // wave-parallel digit select
                    int l = tid;
                    unsigned int h4 = S.hist[4 * l] + S.hist[4 * l + 1]
                                    + S.hist[4 * l + 2] + S.hist[4 * l + 3];
                    unsigned int Ssum = h4;       // suffix sum over lane groups
#pragma unroll
                    for (int off = 1; off < 64; off <<= 1) {
                        unsigned int o = __shfl_down(Ssum, off);
                        Ssum += (l + off < 64) ? o : 0u;
                    }
                    unsigned int rem = S.sh_remaining;
                    unsigned long long ball = __ballot(Ssum >= rem);  // lanes 0..L set
                    int L = 63 - __clzll(ball);
                    if (l == L) {
                        unsigned int rem2 = rem - (Ssum - h4);
                        unsigned int c = 0;
                        for (int dd = 4 * L + 3; dd >= 4 * L; --dd) {
                            c += S.hist[dd];
                            if (c >= rem2) {
                                S.sh_prefix = pre | ((unsigned int)dd << shift);
                                S.sh_remaining = rem2 - (c - S.hist[dd]);
                                break;
                            }
                        }
                    }
                }
                __syncthreads();
            }
            unsigned int vbits = S.sh_prefix;
            unsigned int myc = 0; double mys = 0.0;
            for (int i = tid; i < AA; i += 1024) {
                unsigned int u = S.cl[i];
                if (u > vbits) { myc++; mys += (double)__uint_as_float(u); }
            }
#pragma unroll
            for (int off = 32; off > 0; off >>= 1) {
                myc += __shfl_down(myc, off);
                mys += __shfl_down(mys, off);
            }
            if (lane == 0) { S.red_u[tid >> 6] = myc; S.red_d[tid >> 6] = mys; }
            __syncthreads();
            if (tid == 0) {
                unsigned int cnt_gt = 0; double sum_gt = 0.0;
                for (int w = 0; w < 16; ++w) { cnt_gt += S.red_u[w]; sum_gt += S.red_d[w]; }
                topk = sum_gt + (double)(k - (int)cnt_gt) * (double)__uint_as_float(vbits);
                if (vbits == 0u) {                // rare tie-at-zero path
                    int t = k - (int)cnt_gt, c2 = 0;
                    for (int i = 0; i < AA && c2 < t; ++i) {
                        if (S.cl[i] == 0u) { c2++; if (S.slab[i] > 0) p_t_pos++; }
                    }
                }
            }
        }
        if (tid == 0) {
            int unsampled = AA - np_ - k + p_t_pos;
            double clsb = S.sh_pc + topk + (double)unsampled * (double)logf(81.0f);
            double myb = S.sh_loc + clsb;
            atomicAdd(btot_acc, myb);             // device-scope by default
            atomicAdd(np_acc, np_);
            __threadfence();
            unsigned int t = atomicAdd(ticket, 1u);
            if (t == BB - 1) {                    // last block: all adds happened-before
                double tt = atomicAdd(btot_acc, 0.0);  // returns old = full sum
                int nn = atomicAdd(np_acc, 0);
                out[0] = (float)(tt / (double)nn);
            }
        }
    }
}

extern "C" void kernel_launch(void* const* d_in, const int* in_sizes, int n_in,
                              void* d_out, int out_size, void* d_ws, size_t ws_size,
                              hipStream_t stream) {
    (void)in_sizes; (void)n_in; (void)out_size; (void)ws_size;
    const float* loc_pred  = (const float*)d_in[0];
    const float* conf_pred = (const float*)d_in[1];
    const float* anchors   = (const float*)d_in[2];
    const float* gt_boxes  = (const float*)d_in[3];
    const int*   gt_labels = (const int*)d_in[4];

    char* ws = (char*)d_ws;
    unsigned int*  bestp    = (unsigned int*)(ws + 0);
    unsigned char* bestg    = (unsigned char*)(ws + 8192);
    float*         cls_l    = (float*)(ws + 567040);
    unsigned int*  ready    = (unsigned int*)(ws + 2802432);
    unsigned int*  ticket   = (unsigned int*)(ws + 2806528);
    double*        btot_acc = (double*)(ws + 2806536);
    int*           np_acc   = (int*)(ws + 2806544);

    kInit <<<1, 256, 0, stream>>>(ready);         // zeros ready+ticket+btot+np
    kFused<<<TOT_BLOCKS, 1024, 0, stream>>>(loc_pred, conf_pred, anchors,
        gt_boxes, gt_labels, bestg, bestp, cls_l, ready, ticket, btot_acc,
        np_acc, (float*)d_out);
}

// Round 7
// 314.387 us; speedup vs baseline: 2.2937x; 2.2937x over previous
//
#include <hip/hip_runtime.h>
#include <math.h>

// Keep box arithmetic bit-identical to numpy fp32 (no fma contraction):
// matching decisions (iou > 0.5, argmax) must not flip.
#pragma clang fp contract(off)

#define BB 64
#define AA 8732
#define CC 81
#define GG 32
#define A_BLOCKS 35                 // ceil(8732/256)
#define KC_GRID 1536                // C role: 6-7 blocks/CU at 20.7 KB LDS
#define KA1_BLOCKS (BB*A_BLOCKS)    // 2240
#define KA2_BLOCKS (BB*GG/4)        // 512
#define TOT_BLOCKS (KC_GRID+KA1_BLOCKS+KA2_BLOCKS)
#define ROWS_PC 64                  // conf rows per kC chunk
#define KC_CHUNKS (BB*AA/ROWS_PC)   // 8732 chunks, exact
#define CHUNK_F4 (ROWS_PC*81/4)     // 1296 float4 per chunk, exact

// ---- workspace layout (bytes) ----
// [0,8192)           bestp  u32[B*G]
// [8192,567040)      bestg  u8[B*A]
// [567040,2802432)   cls_l  f32[B*A]
// [2802432,2802436)  ticket u32      (zeroed by kAC block 0)
// [2802440,2802448)  btot   f64
// [2802448,2802452)  np_acc i32

__device__ __forceinline__ void iou_upd(const float4 an, int a,
    float gx1, float gy1, float gx2, float gy2, float gar2,
    float& bi, float& bu, int& ba)
{
    float ax1 = an.x - an.z / 2.0f, ay1 = an.y - an.w / 2.0f;
    float ax2 = an.x + an.z / 2.0f, ay2 = an.y + an.w / 2.0f;
    float aar = (ax2 - ax1) * (ay2 - ay1);
    float ltx = fmaxf(gx1, ax1), lty = fmaxf(gy1, ay1);
    float rbx = fminf(gx2, ax2), rby = fminf(gy2, ay2);
    float w = fmaxf(rbx - ltx, 0.0f), h = fmaxf(rby - lty, 0.0f);
    float inter = w * h;
    float uni = gar2 + aar - inter;
    if (inter * bu > bi * uni) { bi = inter; bu = uni; ba = a; }  // strict >: first max
}

// ---------------- Kernel AC: one dispatch, three roles ----------------
// (Round-4 verified configuration, 313.98 us. Round-6's fused
// producer/consumer variant regressed 5x: ~9.4k device-scope
// __threadfence releases -> per-signal L2 writebacks serialized the chip.
// Two stream-ordered dispatches need NO fences; reverted permanently.)
// blocks [0,1536):     C  — conf logsumexp, SINGLE 20.7 KB buffer (7 blocks/CU)
//                      with 1-iteration reg prefetch; 2 barriers/iter; load
//                      latency hides under compute + 24-28 resident waves/CU.
// blocks [1536,3776):  A1 — per-anchor best gt (thread per anchor)
// blocks [3776,4288):  A2 — per-gt best anchor (wave per (b,g)), 8x-batched
// iou compare by cross-multiplication: iou1>iou2 <=> i1*u2 > i2*u1 (all >0);
// threshold iou>0.5 <=> 2*i > u. No division anywhere.
__global__ __launch_bounds__(256) void kAC(const float* __restrict__ anchors,
    const float* __restrict__ gt_boxes, const float* __restrict__ conf,
    unsigned char* __restrict__ bestg, unsigned int* __restrict__ bestp,
    float* __restrict__ cls_l, unsigned int* __restrict__ ticket,
    double* __restrict__ btot_acc, int* __restrict__ np_acc)
{
    __shared__ float buf[ROWS_PC * 81];           // 20736 B (7 blocks/CU)
    int tid = threadIdx.x;
    if (blockIdx.x == 0 && tid == 0) {            // init for kBE's final reduce
        *ticket = 0u; *btot_acc = 0.0; *np_acc = 0;
    }
    if (blockIdx.x < KC_GRID) {
        // ---- role C ----
        const float4* __restrict__ src4 = (const float4*)conf;
        float4* buf4 = (float4*)buf;
        float4 r0, r1, r2, r3, r4, r5;
        int c0 = blockIdx.x;
        {   // prologue: load chunk c0 -> regs -> buf
            size_t b4 = (size_t)c0 * CHUNK_F4;
            r0 = src4[b4 + tid];        r1 = src4[b4 + tid + 256];
            r2 = src4[b4 + tid + 512];  r3 = src4[b4 + tid + 768];
            r4 = src4[b4 + tid + 1024];
            if (tid < 16) r5 = src4[b4 + tid + 1280];
            buf4[tid] = r0; buf4[tid + 256] = r1; buf4[tid + 512] = r2;
            buf4[tid + 768] = r3; buf4[tid + 1024] = r4;
            if (tid < 16) buf4[tid + 1280] = r5;
        }
        for (int c = c0; c < KC_CHUNKS; c += KC_GRID) {
            int nx = c + KC_GRID;
            __syncthreads();                      // buf writes visible to all
            if (nx < KC_CHUNKS) {                 // issue next-chunk loads NOW;
                size_t b4 = (size_t)nx * CHUNK_F4;//  latency hides under compute
                r0 = src4[b4 + tid];        r1 = src4[b4 + tid + 256];
                r2 = src4[b4 + tid + 512];  r3 = src4[b4 + tid + 768];
                r4 = src4[b4 + tid + 1024];
                if (tid < 16) r5 = src4[b4 + tid + 1280];
            }
            {   // compute chunk c from buf (verified 21/20/20/20 split)
                int r = tid >> 2, q = tid & 3;    // 4 threads per row
                const float* row = buf + r * 81;
                int kstart = (q == 0) ? 0 : 21 + (q - 1) * 20;
                float s = 0.0f;
#pragma unroll
                for (int k = 0; k < 20; ++k) s += __expf(row[kstart + k]);
                if (q == 0) s += __expf(row[20]);
                s += __shfl_xor(s, 1);
                s += __shfl_xor(s, 2);
                if (q == 0)
                    cls_l[c * ROWS_PC + r] = __logf(s) - row[0];  // idx01=0 for negatives
            }
            if (nx < KC_CHUNKS) {
                __syncthreads();                  // compute reads done; buf reusable
                buf4[tid] = r0; buf4[tid + 256] = r1; buf4[tid + 512] = r2;
                buf4[tid + 768] = r3; buf4[tid + 1024] = r4;
                if (tid < 16) buf4[tid + 1280] = r5;
            }
        }
    } else if (blockIdx.x < KC_GRID + KA1_BLOCKS) {
        // ---- role A1 ---- (gt tiles overlay the C-role LDS buffer)
        float4* gco = (float4*)buf;               // 32 float4
        float* gar = buf + 128;                   // 32 floats
        int blk = blockIdx.x - KC_GRID;
        int b = blk / A_BLOCKS, ca = blk % A_BLOCKS;
        int a = ca * 256 + tid;
        if (tid < GG) {
            float4 gb = ((const float4*)gt_boxes)[b * GG + tid];
            float x1 = gb.x - gb.z / 2.0f, y1 = gb.y - gb.w / 2.0f;
            float x2 = gb.x + gb.z / 2.0f, y2 = gb.y + gb.w / 2.0f;
            gco[tid] = make_float4(x1, y1, x2, y2);
            gar[tid] = (x2 - x1) * (y2 - y1);     // same rounding as reference
        }
        __syncthreads();
        if (a >= AA) return;
        float4 an = ((const float4*)anchors)[a];
        float ax1 = an.x - an.z / 2.0f, ay1 = an.y - an.w / 2.0f;
        float ax2 = an.x + an.z / 2.0f, ay2 = an.y + an.w / 2.0f;
        float aar = (ax2 - ax1) * (ay2 - ay1);
        float bi = -1.0f, bu = 1.0f; int bgi = 0; // first compare takes g=0
#pragma unroll
        for (int g = 0; g < GG; ++g) {
            float4 cbox = gco[g];
            float ltx = fmaxf(cbox.x, ax1), lty = fmaxf(cbox.y, ay1);
            float rbx = fminf(cbox.z, ax2), rby = fminf(cbox.w, ay2);
            float w = fmaxf(rbx - ltx, 0.0f), h = fmaxf(rby - lty, 0.0f);
            float inter = w * h;
            float uni = gar[g] + aar - inter;
            if (inter * bu > bi * uni) { bi = inter; bu = uni; bgi = g; }
        }
        bestg[b * AA + a] = (2.0f * bi > bu) ? (unsigned char)bgi : (unsigned char)0xFF;
    } else {
        // ---- role A2 ----
        int wv = tid >> 6, lane = tid & 63;
        int pair = (blockIdx.x - KC_GRID - KA1_BLOCKS) * 4 + wv;   // 0..2047
        int b = pair >> 5, g = pair & 31;
        float4 gb = ((const float4*)gt_boxes)[b * GG + g];
        float gx1 = gb.x - gb.z / 2.0f, gy1 = gb.y - gb.w / 2.0f;
        float gx2 = gb.x + gb.z / 2.0f, gy2 = gb.y + gb.w / 2.0f;
        float gar2 = (gx2 - gx1) * (gy2 - gy1);
        const float4* __restrict__ A4 = (const float4*)anchors;
        float bi = -1.0f, bu = 1.0f; int ba = 0;
        // 8732 = 64*136 + 28; 136 = 8*17: a = lane + 64k ascending (tie order kept)
        for (int k0 = 0; k0 < 136; k0 += 8) {
            int a0 = lane + 64 * k0;
            float4 v0 = A4[a0];                   // 8 independent loads in flight
            float4 v1 = A4[a0 + 64];
            float4 v2 = A4[a0 + 128];
            float4 v3 = A4[a0 + 192];
            float4 v4 = A4[a0 + 256];
            float4 v5 = A4[a0 + 320];
            float4 v6 = A4[a0 + 384];
            float4 v7 = A4[a0 + 448];
            iou_upd(v0, a0,       gx1, gy1, gx2, gy2, gar2, bi, bu, ba);
            iou_upd(v1, a0 + 64,  gx1, gy1, gx2, gy2, gar2, bi, bu, ba);
            iou_upd(v2, a0 + 128, gx1, gy1, gx2, gy2, gar2, bi, bu, ba);
            iou_upd(v3, a0 + 192, gx1, gy1, gx2, gy2, gar2, bi, bu, ba);
            iou_upd(v4, a0 + 256, gx1, gy1, gx2, gy2, gar2, bi, bu, ba);
            iou_upd(v5, a0 + 320, gx1, gy1, gx2, gy2, gar2, bi, bu, ba);
            iou_upd(v6, a0 + 384, gx1, gy1, gx2, gy2, gar2, bi, bu, ba);
            iou_upd(v7, a0 + 448, gx1, gy1, gx2, gy2, gar2, bi, bu, ba);
        }
        if (lane < 28) {                          // tail: a = 8704..8731
            int a = 8704 + lane;
            iou_upd(A4[a], a, gx1, gy1, gx2, gy2, gar2, bi, bu, ba);
        }
        // wave butterfly-reduce, lexicographic (iou desc, a asc)
#pragma unroll
        for (int off = 32; off > 0; off >>= 1) {
            float oi = __shfl_down(bi, off);
            float ou = __shfl_down(bu, off);
            int   oa = __shfl_down(ba, off);
            float p1 = oi * bu, p2 = bi * ou;
            bool take = (p1 > p2) || ((p1 == p2) && (oa < ba));
            if (take) { bi = oi; bu = ou; ba = oa; }
        }
        if (lane == 0) bestp[pair] = (unsigned int)ba;
    }
}

// ---------------- Kernel BE: finalize + radix top-k + final reduce, fused ----------------
// One block per image, 1024 threads. Keys/labels live only in LDS. Radix
// pass-1 histogram uses leader-ballot aggregation (one atomic per dominant
// digit per wave-iteration); spread digits fall back to per-lane atomics.
__global__ __launch_bounds__(1024, 4) void kBE(const float* __restrict__ anchors,
    const float* __restrict__ gt_boxes, const int* __restrict__ gt_labels,
    const float* __restrict__ loc_pred, const unsigned char* __restrict__ bestg,
    const unsigned int* __restrict__ bestp, const float* __restrict__ cls_l,
    const float* __restrict__ conf, unsigned int* __restrict__ ticket,
    double* __restrict__ btot_acc, int* __restrict__ np_acc,
    float* __restrict__ out)
{
    int b = blockIdx.x, tid = threadIdx.x, lane = tid & 63;
    __shared__ unsigned int cl[AA];               // 34928 B
    __shared__ unsigned char slab[AA];            // 8732 B
    __shared__ unsigned int hist[256];
    __shared__ float gcx[GG], gcy[GG], gw[GG], gh[GG];
    __shared__ int glab[GG];
    __shared__ unsigned int bp[GG];
    __shared__ double red_d[16], red_p[16];
    __shared__ int red_i[16];
    __shared__ unsigned int red_u[16];
    __shared__ unsigned int sh_prefix, sh_remaining;
    __shared__ int sh_np;
    __shared__ double sh_loc, sh_pc;

    if (tid < GG) {
        float4 gb = ((const float4*)gt_boxes)[b * GG + tid];
        gcx[tid] = gb.x; gcy[tid] = gb.y; gw[tid] = gb.z; gh[tid] = gb.w;
        glab[tid] = gt_labels[b * GG + tid];
        bp[tid] = bestp[b * GG + tid];
    }
    __syncthreads();

    // ---- phase B: labels, loc loss, keys, positive CE ----
    double lsum = 0.0, pc = 0.0; int pcount = 0;
    for (int a = tid; a < AA; a += 1024) {
        int gf = -1;
#pragma unroll
        for (int g = 0; g < GG; ++g)
            if (bp[g] == (unsigned int)a) gf = g; // ascending: largest g wins
        int gsel;
        if (gf >= 0) gsel = gf;
        else {
            unsigned char bg = bestg[b * AA + a];
            gsel = (bg == 0xFF) ? -1 : (int)bg;
        }
        int lab = 0;
        if (gsel >= 0) {
            lab = glab[gsel];                     // labels in 1..C-1 -> positive
            float4 an = ((const float4*)anchors)[a];
            float e0 = (gcx[gsel] - an.x) / an.z;
            float e1 = (gcy[gsel] - an.y) / an.w;
            float e2 = logf(gw[gsel]) - logf(an.z);
            float e3 = logf(gh[gsel]) - logf(an.w);
            float4 lp = ((const float4*)loc_pred)[b * AA + a];
            float d0 = lp.x - e0, d1 = lp.y - e1, d2 = lp.z - e2, d3 = lp.w - e3;
            float t = 0.0f, ad;
            ad = fabsf(d0); t += (ad < 1.0f) ? 0.5f * d0 * d0 : ad - 0.5f;
            ad = fabsf(d1); t += (ad < 1.0f) ? 0.5f * d1 * d1 : ad - 0.5f;
            ad = fabsf(d2); t += (ad < 1.0f) ? 0.5f * d2 * d2 : ad - 0.5f;
            ad = fabsf(d3); t += (ad < 1.0f) ? 0.5f * d3 * d3 : ad - 0.5f;
            lsum += (double)t;
            pcount++;
        }
        slab[a] = (unsigned char)lab;
        float sv = cls_l[b * AA + a];
        if (lab > 0) {
            size_t rowb = ((size_t)(b * AA + a)) * 81;
            pc += (double)(sv + conf[rowb] - conf[rowb + lab]);  // lse - conf[label]
            cl[a] = 0u;                           // positives excluded from mining
        } else {
            cl[a] = __float_as_uint(fmaxf(sv, 0.0f));  // guard tiny negative rounding
        }
    }
#pragma unroll
    for (int off = 32; off > 0; off >>= 1) {
        lsum += __shfl_down(lsum, off);
        pc += __shfl_down(pc, off);
        pcount += __shfl_down(pcount, off);
    }
    if (lane == 0) { red_d[tid >> 6] = lsum; red_p[tid >> 6] = pc; red_i[tid >> 6] = pcount; }
    __syncthreads();
    if (tid == 0) {
        double L = 0.0, C = 0.0; int P = 0;
        for (int w = 0; w < 16; ++w) { L += red_d[w]; C += red_p[w]; P += red_i[w]; }
        sh_loc = L; sh_pc = C; sh_np = P;
        sh_prefix = 0u;
        sh_remaining = (unsigned int)min(3 * P, AA - 1);
    }
    __syncthreads();
    int np_ = sh_np;
    int k = min(3 * np_, AA - 1);                 // num_neg = min(3*num_pos, A-1)

    // ---- phase E: radix-select top-k ----
    double topk = 0.0;
    int p_t_pos = 0;                              // positives inside neg_mask (tie at 0)
    if (k > 0) {
        for (int shift = 24; shift >= 0; shift -= 8) {
            if (tid < 256) hist[tid] = 0u;
            __syncthreads();
            unsigned int mask = (shift == 24) ? 0u : (0xFFFFFFFFu << (shift + 8));
            unsigned int pre = sh_prefix;
#pragma unroll
            for (int it = 0; it < 9; ++it) {      // 9*1024 >= 8732; wave-uniform trips
                int i = tid + it * 1024;
                bool in = (i < AA);
                unsigned int u = in ? cl[i] : 0u;
                bool act = in && ((u & mask) == pre);
                unsigned int d = (u >> shift) & 255u;
                unsigned long long actm = __ballot(act);
                while (actm) {                    // aggregate dominant digits
                    int src = __builtin_ctzll(actm);
                    unsigned int d0 = (unsigned int)__shfl((int)d, src);
                    unsigned long long m = __ballot(act && (d == d0));
                    int c = __popcll(m);
                    if (c < 8) break;             // spread digits -> per-lane fallback
                    if (lane == src) atomicAdd(&hist[d0], (unsigned int)c);
                    actm &= ~m;
                }
                if ((actm >> lane) & 1ull) atomicAdd(&hist[d], 1u);
            }
            __syncthreads();
            if (tid < 64) {                       // wave-parallel digit select
                int l = tid;
                unsigned int h4 = hist[4 * l] + hist[4 * l + 1]
                                + hist[4 * l + 2] + hist[4 * l + 3];
                unsigned int S = h4;              // suffix sum over lane groups
#pragma unroll
                for (int off = 1; off < 64; off <<= 1) {
                    unsigned int o = __shfl_down(S, off);
                    S += (l + off < 64) ? o : 0u;
                }
                unsigned int rem = sh_remaining;
                unsigned long long ball = __ballot(S >= rem);  // lanes 0..L set
                int L = 63 - __clzll(ball);
                if (l == L) {
                    unsigned int rem2 = rem - (S - h4);
                    unsigned int c = 0;
                    for (int dd = 4 * L + 3; dd >= 4 * L; --dd) {
                        c += hist[dd];
                        if (c >= rem2) {
                            sh_prefix = pre | ((unsigned int)dd << shift);
                            sh_remaining = rem2 - (c - hist[dd]);
                            break;
                        }
                    }
                }
            }
            __syncthreads();
        }
        unsigned int vbits = sh_prefix;
        unsigned int myc = 0; double mys = 0.0;
        for (int i = tid; i < AA; i += 1024) {
            unsigned int u = cl[i];
            if (u > vbits) { myc++; mys += (double)__uint_as_float(u); }
        }
#pragma unroll
        for (int off = 32; off > 0; off >>= 1) {
            myc += __shfl_down(myc, off);
            mys += __shfl_down(mys, off);
        }
        if (lane == 0) { red_u[tid >> 6] = myc; red_d[tid >> 6] = mys; }
        __syncthreads();
        if (tid == 0) {
            unsigned int cnt_gt = 0; double sum_gt = 0.0;
            for (int w = 0; w < 16; ++w) { cnt_gt += red_u[w]; sum_gt += red_d[w]; }
            topk = sum_gt + (double)(k - (int)cnt_gt) * (double)__uint_as_float(vbits);
            if (vbits == 0u) {                    // rare tie-at-zero path
                int t = k - (int)cnt_gt, c2 = 0;
                for (int i = 0; i < AA && c2 < t; ++i) {
                    if (cl[i] == 0u) { c2++; if (slab[i] > 0) p_t_pos++; }
                }
            }
        }
    }
    if (tid == 0) {
        int unsampled = AA - np_ - k + p_t_pos;
        double clsb = sh_pc + topk + (double)unsampled * (double)logf(81.0f);
        double myb = sh_loc + clsb;
        atomicAdd(btot_acc, myb);                 // device-scope by default
        atomicAdd(np_acc, np_);
        __threadfence();
        unsigned int t = atomicAdd(ticket, 1u);
        if (t == BB - 1) {                        // last block: all adds happened-before
            double tt = atomicAdd(btot_acc, 0.0); // returns old = full sum
            int nn = atomicAdd(np_acc, 0);
            out[0] = (float)(tt / (double)nn);
        }
    }
}

extern "C" void kernel_launch(void* const* d_in, const int* in_sizes, int n_in,
                              void* d_out, int out_size, void* d_ws, size_t ws_size,
                              hipStream_t stream) {
    (void)in_sizes; (void)n_in; (void)out_size; (void)ws_size;
    const float* loc_pred  = (const float*)d_in[0];
    const float* conf_pred = (const float*)d_in[1];
    const float* anchors   = (const float*)d_in[2];
    const float* gt_boxes  = (const float*)d_in[3];
    const int*   gt_labels = (const int*)d_in[4];

    char* ws = (char*)d_ws;
    unsigned int*  bestp    = (unsigned int*)(ws + 0);
    unsigned char* bestg    = (unsigned char*)(ws + 8192);
    float*         cls_l    = (float*)(ws + 567040);
    unsigned int*  ticket   = (unsigned int*)(ws + 2802432);
    double*        btot_acc = (double*)(ws + 2802440);
    int*           np_acc   = (int*)(ws + 2802448);

    kAC<<<TOT_BLOCKS, 256, 0, stream>>>(anchors, gt_boxes, conf_pred,
        bestg, bestp, cls_l, ticket, btot_acc, np_acc);
    kBE<<<BB, 1024, 0, stream>>>(anchors, gt_boxes, gt_labels, loc_pred,
        bestg, bestp, cls_l, conf_pred, ticket, btot_acc, np_acc, (float*)d_out);
}